// Round 15
// baseline (403.816 us; speedup 1.0000x reference)
//
#include <hip/hip_runtime.h>
#include <hip/hip_bf16.h>

// Problem: B=128, T=256, D=1024.  TOK = B*T = 32768.
// keys = x@Wk.T+bk ; queries = x@Wq.T+bq ; values = x@Wv.T+bv
// S = tril(Q K^T / 32) ; P = softmax(S) ; out = P V   (fp32 out)
//
// CONFIG: locked 398us pipeline + S stored as bf16 (halves the S round-trip:
// 256MB -> 128MB).  qkv structure-space closed at ~300us (687 TF) after 9
// variants; qkv256/cvt/pv byte-identical to the 398us run.

typedef __attribute__((ext_vector_type(4))) float f32x4;
typedef __attribute__((ext_vector_type(8))) short s16x8;
typedef unsigned short u16;

__device__ inline u16 f2bf(float f) {
    union { __hip_bfloat16 h; u16 u; } c;
    c.h = __float2bfloat16(f);
    return c.u;
}

__device__ inline float bf2f(u16 u) {
    union { unsigned int i; float f; } c;
    c.i = ((unsigned int)u) << 16;
    return c.f;
}

// async global->LDS DMA, 16B/lane, dest = wave-uniform base + lane*16
__device__ __forceinline__ void stage16(const void* g, void* l) {
    __builtin_amdgcn_global_load_lds((const __attribute__((address_space(1))) void*)g,
                                     (__attribute__((address_space(3))) void*)l, 16, 0, 0);
}

#define MFMA(a_, b_, c_) (c_) = __builtin_amdgcn_mfma_f32_16x16x32_bf16((a_), (b_), (c_), 0, 0, 0)

// ---------------- fp32 -> bf16 convert (x) ----------------
__global__ __launch_bounds__(256) void cvt_f32_bf16(const float* __restrict__ in,
                                                    u16* __restrict__ out, int n4) {
    int stride = gridDim.x * blockDim.x;
    for (int i = blockIdx.x * blockDim.x + threadIdx.x; i < n4; i += stride) {
        float4 v = reinterpret_cast<const float4*>(in)[i];
        ushort4 o = make_ushort4(f2bf(v.x), f2bf(v.y), f2bf(v.z), f2bf(v.w));
        reinterpret_cast<ushort4*>(out)[i] = o;
    }
}

// ---------------- fp32 -> bf16 convert, 3 weights in one launch ----------------
__global__ __launch_bounds__(256) void cvt_w3(const float* __restrict__ Wk,
                                              const float* __restrict__ Wq,
                                              const float* __restrict__ Wv,
                                              u16* __restrict__ Wb) {
    const int wsel = blockIdx.x / 512;          // 0:K 1:Q 2:V
    const int blk  = blockIdx.x % 512;
    const float* src = (wsel == 0) ? Wk : (wsel == 1) ? Wq : Wv;
    u16* dst = Wb + (size_t)wsel * 1048576;
    const int i = blk * 256 + threadIdx.x;
    {
        float4 v = reinterpret_cast<const float4*>(src)[i];
        ushort4 o = make_ushort4(f2bf(v.x), f2bf(v.y), f2bf(v.z), f2bf(v.w));
        reinterpret_cast<ushort4*>(dst)[i] = o;
        float4 v2 = reinterpret_cast<const float4*>(src)[i + 131072];
        ushort4 o2 = make_ushort4(f2bf(v2.x), f2bf(v2.y), f2bf(v2.z), f2bf(v2.w));
        reinterpret_cast<ushort4*>(dst)[i + 131072] = o2;
    }
}

// ======== R7 qkv256 VERBATIM (best measured: ~300us, 687 TF) ========
__global__ __launch_bounds__(512, 2) void qkv256(const u16* __restrict__ X, const u16* __restrict__ W3,
                                                 const float* __restrict__ biasK,
                                                 const float* __restrict__ biasQ,
                                                 const float* __restrict__ biasV,
                                                 u16* __restrict__ Kb, u16* __restrict__ Qb,
                                                 u16* __restrict__ Vt) {
    extern __shared__ char lds[];  // 131072 B = 4 bufs * 32768

    const int bid = blockIdx.x;
    const int swz = (bid & 7) * 192 + (bid >> 3);  // 1536 % 8 == 0: bijective XCD swizzle
    const int mt = swz / 12, nt2 = swz % 12;
    const int nmat = nt2 >> 2, ncol = nt2 & 3;
    const u16* Asrc = X + (size_t)mt * 256 * 1024;
    const u16* Bsrc = W3 + (size_t)nmat * 1048576 + (size_t)ncol * 256 * 1024;

    const int tid  = threadIdx.x;
    const int lane = tid & 63, w = tid >> 6;
    const int wr = w >> 2, wc = w & 3;
    const int l15 = lane & 15, l16 = lane >> 4;

    const int lds_ro = l15 * 64 + ((l16 ^ ((l15 >> 1) & 3)) << 4);
    const int aoff = wr * 128 * 64 + lds_ro;
    const int boff = 16384 + wc * 64 * 64 + lds_ro;

    const int isB = w >> 2;
    const u16* dsrc = isB ? Bsrc : Asrc;
    const int drow  = (w & 3) * 64 + (lane >> 2);
    const int dslot = ((lane & 3) ^ ((lane >> 3) & 3)) * 8;
    const u16* dptr0 = dsrc + (size_t)drow * 1024 + dslot;
    const int dlds = isB * 16384 + (w & 3) * 4096;

#define STAGE(u_) do {                                                            \
        char* bb_ = lds + (((u_) & 3) * 32768) + dlds;                            \
        const u16* gp_ = dptr0 + (size_t)(u_) * 32;                               \
        stage16(gp_,             bb_);                                            \
        stage16(gp_ + 16 * 1024, bb_ + 1024);                                     \
        stage16(gp_ + 32 * 1024, bb_ + 2048);                                     \
        stage16(gp_ + 48 * 1024, bb_ + 3072);                                     \
    } while (0)

#define RDA(d_, bp_, fm_) d_[fm_] = *(const s16x8*)((bp_) + aoff + (fm_) * 1024)
#define RDB(d_, bp_, fn_) d_[fn_] = *(const s16x8*)((bp_) + boff + (fn_) * 1024)

#define MM4(fm_, a_, b_) do {                                                     \
        MFMA(a_[fm_], b_[0], acc[fm_][0]);                                        \
        MFMA(a_[fm_], b_[1], acc[fm_][1]);                                        \
        MFMA(a_[fm_], b_[2], acc[fm_][2]);                                        \
        MFMA(a_[fm_], b_[3], acc[fm_][3]);                                        \
    } while (0)

#define STEP(u_, AR_, BR_, AM_, BM_) do {                                         \
        if ((u_) + 2 <= 31) STAGE((u_) + 2);                                      \
        const char* bp_ = lds + (((u_) & 3) * 32768);                             \
        RDA(AR_, bp_, 0); RDA(AR_, bp_, 1); RDA(AR_, bp_, 2);                     \
        MM4(0, AM_, BM_); MM4(1, AM_, BM_);                                       \
        RDA(AR_, bp_, 3); RDA(AR_, bp_, 4); RDA(AR_, bp_, 5);                     \
        MM4(2, AM_, BM_); MM4(3, AM_, BM_);                                       \
        RDA(AR_, bp_, 6); RDA(AR_, bp_, 7); RDB(BR_, bp_, 0);                     \
        MM4(4, AM_, BM_); MM4(5, AM_, BM_);                                       \
        RDB(BR_, bp_, 1); RDB(BR_, bp_, 2); RDB(BR_, bp_, 3);                     \
        MM4(6, AM_, BM_); MM4(7, AM_, BM_);                                       \
        if ((u_) <= 29) asm volatile("s_waitcnt vmcnt(4)" ::: "memory");          \
        else            asm volatile("s_waitcnt vmcnt(0)" ::: "memory");          \
        __builtin_amdgcn_s_barrier();                                             \
    } while (0)

    f32x4 acc[8][4] = {};
    s16x8 a0[8], b0[4], a1[8], b1[4];

    STAGE(0); STAGE(1); STAGE(2);
    asm volatile("s_waitcnt vmcnt(4)" ::: "memory");   // t0,t1 done; t2 in flight
    __builtin_amdgcn_s_barrier();
    {
        const char* bp_ = lds;
        RDA(a0, bp_, 0); RDA(a0, bp_, 1); RDA(a0, bp_, 2); RDA(a0, bp_, 3);
        RDA(a0, bp_, 4); RDA(a0, bp_, 5); RDA(a0, bp_, 6); RDA(a0, bp_, 7);
        RDB(b0, bp_, 0); RDB(b0, bp_, 1); RDB(b0, bp_, 2); RDB(b0, bp_, 3);
    }

    for (int tt = 0; tt < 15; ++tt) {
        STEP(2 * tt + 1, a1, b1, a0, b0);
        STEP(2 * tt + 2, a0, b0, a1, b1);
    }
    STEP(31, a1, b1, a0, b0);
    MM4(0, a1, b1); MM4(1, a1, b1); MM4(2, a1, b1); MM4(3, a1, b1);
    MM4(4, a1, b1); MM4(5, a1, b1); MM4(6, a1, b1); MM4(7, a1, b1);

#undef STAGE
#undef RDA
#undef RDB
#undef MM4
#undef STEP

    const float* bias = (nmat == 0) ? biasK : (nmat == 1) ? biasQ : biasV;
    u16* outKQ = (nmat == 0) ? Kb : Qb;
    const int colbase = ncol * 256 + wc * 64;
#pragma unroll
    for (int FM = 0; FM < 8; ++FM) {
#pragma unroll
        for (int fn = 0; fn < 4; ++fn) {
            const int col = colbase + fn * 16 + l15;
            const float bvv = bias[col];
            const int rbase = mt * 256 + wr * 128 + FM * 16 + (l16 << 2);
#pragma unroll
            for (int j = 0; j < 4; ++j) {
                const int row = rbase + j;
                const u16 hb = f2bf(acc[FM][fn][j] + bvv);
                if (nmat == 2) {
                    const int b = row >> 8, tt2 = row & 255;
                    Vt[(size_t)b * 262144 + (size_t)col * 256 + tt2] = hb;
                } else {
                    outKQ[(size_t)row * 1024 + col] = hb;
                }
            }
        }
    }
}

// ---------------- R1 reg-staged 128x128 mainloop (scores / pv) ----------------
__device__ inline void gemm_mainloop(const u16* __restrict__ Ap, const u16* __restrict__ Bp,
                                     int lda, int ldb, int kLen,
                                     u16* As, u16* Bs, f32x4 (&acc)[4][4]) {
    const int tid  = threadIdx.x;
    const int lane = tid & 63;
    const int wr   = (tid >> 7) & 1;
    const int wc   = (tid >> 6) & 1;
    const int sr   = tid >> 3;
    const int sc   = (tid & 7) << 3;

    for (int k0 = 0; k0 < kLen; k0 += 64) {
#pragma unroll
        for (int it = 0; it < 4; ++it) {
            int r = it * 32 + sr;
            *reinterpret_cast<s16x8*>(&As[r * 64 + sc]) =
                *reinterpret_cast<const s16x8*>(&Ap[(size_t)r * lda + k0 + sc]);
            *reinterpret_cast<s16x8*>(&Bs[r * 64 + sc]) =
                *reinterpret_cast<const s16x8*>(&Bp[(size_t)r * ldb + k0 + sc]);
        }
        __syncthreads();
#pragma unroll
        for (int kk = 0; kk < 64; kk += 32) {
            const int kcol = kk + (lane >> 4) * 8;
            s16x8 a[4], bfr[4];
#pragma unroll
            for (int m = 0; m < 4; ++m)
                a[m] = *reinterpret_cast<const s16x8*>(&As[(wr * 64 + m * 16 + (lane & 15)) * 64 + kcol]);
#pragma unroll
            for (int n = 0; n < 4; ++n)
                bfr[n] = *reinterpret_cast<const s16x8*>(&Bs[(wc * 64 + n * 16 + (lane & 15)) * 64 + kcol]);
#pragma unroll
            for (int m = 0; m < 4; ++m)
#pragma unroll
                for (int n = 0; n < 4; ++n)
                    acc[m][n] = __builtin_amdgcn_mfma_f32_16x16x32_bf16(a[m], bfr[n], acc[m][n], 0, 0, 0);
        }
        __syncthreads();
    }
}

// ---------------- scores: S = tril(Q K^T * 1/32) per batch, bf16 out ----------------
__global__ __launch_bounds__(256) void scores_gemm(const u16* __restrict__ Qb,
                                                   const u16* __restrict__ Kb,
                                                   u16* __restrict__ S) {
    __shared__ u16 As[128 * 64];
    __shared__ u16 Bs[128 * 64];
    const int bid = blockIdx.x;
    const int b   = bid / 3;
    const int rem = bid % 3;
    const int ti  = (rem == 0) ? 0 : 1;
    const int si  = (rem == 2) ? 1 : 0;
    const u16* Ap = Qb + ((size_t)b * 256 + (size_t)ti * 128) * 1024;
    const u16* Bp = Kb + ((size_t)b * 256 + (size_t)si * 128) * 1024;

    f32x4 acc[4][4] = {};
    gemm_mainloop(Ap, Bp, 1024, 1024, 1024, As, Bs, acc);

    const int tid  = threadIdx.x;
    const int lane = tid & 63;
    const int wr   = (tid >> 7) & 1;
    const int wc   = (tid >> 6) & 1;
    const int r0 = (lane >> 4) << 2;
    const int c0 = lane & 15;
    const float scale = 0.03125f;
    const float NEG = -__builtin_inff();
#pragma unroll
    for (int m = 0; m < 4; ++m) {
#pragma unroll
        for (int n = 0; n < 4; ++n) {
            const int s = si * 128 + wc * 64 + n * 16 + c0;
#pragma unroll
            for (int j = 0; j < 4; ++j) {
                const int t = ti * 128 + wr * 64 + m * 16 + r0 + j;
                float v = acc[m][n][j] * scale;
                if (s > t) v = NEG;
                S[(size_t)b * 65536 + (size_t)t * 256 + s] = f2bf(v);   // bf16(-inf) = 0xFF80
            }
        }
    }
}

// ---------------- row softmax (bf16 S) -> P (bf16), zeros above diagonal ----------------
__global__ __launch_bounds__(256) void softmax_p(const u16* __restrict__ S, u16* __restrict__ P) {
    const int row  = blockIdx.x * 4 + (threadIdx.x >> 6);
    const int lane = threadIdx.x & 63;
    const int b = row >> 8, t = row & 255;
    const u16* Sp = S + (size_t)b * 65536 + (size_t)t * 256;
    const int s0 = lane * 4;
    ushort4 v = reinterpret_cast<const ushort4*>(Sp)[lane];
    const float NEG = -__builtin_inff();
    float x0 = (s0 + 0 <= t) ? bf2f(v.x) : NEG;
    float x1 = (s0 + 1 <= t) ? bf2f(v.y) : NEG;
    float x2 = (s0 + 2 <= t) ? bf2f(v.z) : NEG;
    float x3 = (s0 + 3 <= t) ? bf2f(v.w) : NEG;
    float mx = fmaxf(fmaxf(x0, x1), fmaxf(x2, x3));
#pragma unroll
    for (int off = 1; off < 64; off <<= 1) mx = fmaxf(mx, __shfl_xor(mx, off, 64));
    float e0 = (s0 + 0 <= t) ? __expf(x0 - mx) : 0.f;
    float e1 = (s0 + 1 <= t) ? __expf(x1 - mx) : 0.f;
    float e2 = (s0 + 2 <= t) ? __expf(x2 - mx) : 0.f;
    float e3 = (s0 + 3 <= t) ? __expf(x3 - mx) : 0.f;
    float sum = e0 + e1 + e2 + e3;
#pragma unroll
    for (int off = 1; off < 64; off <<= 1) sum += __shfl_xor(sum, off, 64);
    const float inv = 1.0f / sum;
    ushort4 o = make_ushort4(f2bf(e0 * inv), f2bf(e1 * inv), f2bf(e2 * inv), f2bf(e3 * inv));
    reinterpret_cast<ushort4*>(P + (size_t)row * 256)[lane] = o;
}

// ---------------- PV: out = P @ V  (Vt is [b][d][t] so NT) ----------------
__global__ __launch_bounds__(256) void pv_gemm(const u16* __restrict__ P, const u16* __restrict__ Vt,
                                               float* __restrict__ O) {
    __shared__ u16 As[128 * 64];
    __shared__ u16 Bs[128 * 64];
    const int bid = blockIdx.x;
    const int b   = bid >> 4;
    const int r   = bid & 15;
    const int mt  = r >> 3;
    const int ntl = r & 7;
    const u16* Ap = P + (size_t)b * 65536 + (size_t)mt * 128 * 256;
    const u16* Bp = Vt + (size_t)b * 262144 + (size_t)ntl * 128 * 256;
    const int kmax = (mt + 1) * 128;

    f32x4 acc[4][4] = {};
    gemm_mainloop(Ap, Bp, 256, 256, kmax, As, Bs, acc);

    const int tid  = threadIdx.x;
    const int lane = tid & 63;
    const int wr   = (tid >> 7) & 1;
    const int wc   = (tid >> 6) & 1;
    const int r0 = (lane >> 4) << 2;
    const int c0 = lane & 15;
#pragma unroll
    for (int m = 0; m < 4; ++m) {
#pragma unroll
        for (int n = 0; n < 4; ++n) {
            const int d = ntl * 128 + wc * 64 + n * 16 + c0;
#pragma unroll
            for (int j = 0; j < 4; ++j) {
                const int t = mt * 128 + wr * 64 + m * 16 + r0 + j;
                O[((size_t)b * 256 + t) * 1024 + d] = acc[m][n][j];
            }
        }
    }
}

// ---------------- launcher ----------------
extern "C" void kernel_launch(void* const* d_in, const int* in_sizes, int n_in,
                              void* d_out, int out_size, void* d_ws, size_t ws_size,
                              hipStream_t stream) {
    (void)in_sizes; (void)n_in; (void)out_size; (void)ws_size;
    const float* x  = (const float*)d_in[0];
    const float* Wk = (const float*)d_in[1];
    const float* bk = (const float*)d_in[2];
    const float* Wq = (const float*)d_in[3];
    const float* bq = (const float*)d_in[4];
    const float* Wv = (const float*)d_in[5];
    const float* bv = (const float*)d_in[6];
    float* out = (float*)d_out;
    char* ws = (char*)d_ws;

    // ws layout (bytes):
    //   [0,            67108864)  xb  bf16 x [32768][1024]  (dead after qkv)
    //   overlay after qkv: S bf16 [128][256][256] at 0 ; P bf16 at 33554432
    //   [67108864,     73400320)  Wb  bf16 Wk|Wq|Wv
    //   [73400320,    140509184)  Kb ; [140509184, 207618048) Qb
    //   [207618048,   274726912)  Vt  bf16 values^T [128][1024][256]
    u16*   xb = (u16*)(ws + 0);
    u16*   Wb = (u16*)(ws + 67108864);
    u16*   Kb = (u16*)(ws + 73400320);
    u16*   Qb = (u16*)(ws + 140509184);
    u16*   Vt = (u16*)(ws + 207618048);
    u16*   S  = (u16*)(ws + 0);
    u16*   P  = (u16*)(ws + 33554432);

    cvt_f32_bf16<<<2048, 256, 0, stream>>>(x, xb, 33554432 / 4);
    cvt_w3<<<1536, 256, 0, stream>>>(Wk, Wq, Wv, Wb);
    qkv256<<<1536, 512, 131072, stream>>>(xb, Wb, bk, bq, bv, Kb, Qb, Vt);
    scores_gemm<<<384, 256, 0, stream>>>(Qb, Kb, S);
    softmax_p<<<8192, 256, 0, stream>>>(S, P);
    pv_gemm<<<2048, 256, 0, stream>>>(P, Vt, out);
}

// Round 16
// 397.716 us; speedup vs baseline: 1.0153x; 1.0153x over previous
//
#include <hip/hip_runtime.h>
#include <hip/hip_bf16.h>

// Problem: B=128, T=256, D=1024.  TOK = B*T = 32768.
// keys = x@Wk.T+bk ; queries = x@Wq.T+bq ; values = x@Wv.T+bv
// S = tril(Q K^T / 32) ; P = softmax(S) ; out = P V   (fp32 out)
//
// FINAL (converged) CONFIG — byte-exact revert to the best measured total
// (R14: 398.3us).  Closed directions: qkv structure-space (9 variants ->
// 300-362us band, MfmaUtil 24-30% invariant; two independent structures
// converge at ~300us = 687 TF); tail fusion (2 attempts regressed);
// S-bf16 (null).  S stays f32.

typedef __attribute__((ext_vector_type(4))) float f32x4;
typedef __attribute__((ext_vector_type(8))) short s16x8;
typedef unsigned short u16;

__device__ inline u16 f2bf(float f) {
    union { __hip_bfloat16 h; u16 u; } c;
    c.h = __float2bfloat16(f);
    return c.u;
}

// async global->LDS DMA, 16B/lane, dest = wave-uniform base + lane*16
__device__ __forceinline__ void stage16(const void* g, void* l) {
    __builtin_amdgcn_global_load_lds((const __attribute__((address_space(1))) void*)g,
                                     (__attribute__((address_space(3))) void*)l, 16, 0, 0);
}

#define MFMA(a_, b_, c_) (c_) = __builtin_amdgcn_mfma_f32_16x16x32_bf16((a_), (b_), (c_), 0, 0, 0)

// ---------------- fp32 -> bf16 convert (x) ----------------
__global__ __launch_bounds__(256) void cvt_f32_bf16(const float* __restrict__ in,
                                                    u16* __restrict__ out, int n4) {
    int stride = gridDim.x * blockDim.x;
    for (int i = blockIdx.x * blockDim.x + threadIdx.x; i < n4; i += stride) {
        float4 v = reinterpret_cast<const float4*>(in)[i];
        ushort4 o = make_ushort4(f2bf(v.x), f2bf(v.y), f2bf(v.z), f2bf(v.w));
        reinterpret_cast<ushort4*>(out)[i] = o;
    }
}

// ---------------- fp32 -> bf16 convert, 3 weights in one launch ----------------
__global__ __launch_bounds__(256) void cvt_w3(const float* __restrict__ Wk,
                                              const float* __restrict__ Wq,
                                              const float* __restrict__ Wv,
                                              u16* __restrict__ Wb) {
    const int wsel = blockIdx.x / 512;          // 0:K 1:Q 2:V
    const int blk  = blockIdx.x % 512;
    const float* src = (wsel == 0) ? Wk : (wsel == 1) ? Wq : Wv;
    u16* dst = Wb + (size_t)wsel * 1048576;
    const int i = blk * 256 + threadIdx.x;
    {
        float4 v = reinterpret_cast<const float4*>(src)[i];
        ushort4 o = make_ushort4(f2bf(v.x), f2bf(v.y), f2bf(v.z), f2bf(v.w));
        reinterpret_cast<ushort4*>(dst)[i] = o;
        float4 v2 = reinterpret_cast<const float4*>(src)[i + 131072];
        ushort4 o2 = make_ushort4(f2bf(v2.x), f2bf(v2.y), f2bf(v2.z), f2bf(v2.w));
        reinterpret_cast<ushort4*>(dst)[i + 131072] = o2;
    }
}

// ======== R7 qkv256 VERBATIM (best measured: ~300us, 687 TF) ========
__global__ __launch_bounds__(512, 2) void qkv256(const u16* __restrict__ X, const u16* __restrict__ W3,
                                                 const float* __restrict__ biasK,
                                                 const float* __restrict__ biasQ,
                                                 const float* __restrict__ biasV,
                                                 u16* __restrict__ Kb, u16* __restrict__ Qb,
                                                 u16* __restrict__ Vt) {
    extern __shared__ char lds[];  // 131072 B = 4 bufs * 32768

    const int bid = blockIdx.x;
    const int swz = (bid & 7) * 192 + (bid >> 3);  // 1536 % 8 == 0: bijective XCD swizzle
    const int mt = swz / 12, nt2 = swz % 12;
    const int nmat = nt2 >> 2, ncol = nt2 & 3;
    const u16* Asrc = X + (size_t)mt * 256 * 1024;
    const u16* Bsrc = W3 + (size_t)nmat * 1048576 + (size_t)ncol * 256 * 1024;

    const int tid  = threadIdx.x;
    const int lane = tid & 63, w = tid >> 6;
    const int wr = w >> 2, wc = w & 3;
    const int l15 = lane & 15, l16 = lane >> 4;

    const int lds_ro = l15 * 64 + ((l16 ^ ((l15 >> 1) & 3)) << 4);
    const int aoff = wr * 128 * 64 + lds_ro;
    const int boff = 16384 + wc * 64 * 64 + lds_ro;

    const int isB = w >> 2;
    const u16* dsrc = isB ? Bsrc : Asrc;
    const int drow  = (w & 3) * 64 + (lane >> 2);
    const int dslot = ((lane & 3) ^ ((lane >> 3) & 3)) * 8;
    const u16* dptr0 = dsrc + (size_t)drow * 1024 + dslot;
    const int dlds = isB * 16384 + (w & 3) * 4096;

#define STAGE(u_) do {                                                            \
        char* bb_ = lds + (((u_) & 3) * 32768) + dlds;                            \
        const u16* gp_ = dptr0 + (size_t)(u_) * 32;                               \
        stage16(gp_,             bb_);                                            \
        stage16(gp_ + 16 * 1024, bb_ + 1024);                                     \
        stage16(gp_ + 32 * 1024, bb_ + 2048);                                     \
        stage16(gp_ + 48 * 1024, bb_ + 3072);                                     \
    } while (0)

#define RDA(d_, bp_, fm_) d_[fm_] = *(const s16x8*)((bp_) + aoff + (fm_) * 1024)
#define RDB(d_, bp_, fn_) d_[fn_] = *(const s16x8*)((bp_) + boff + (fn_) * 1024)

#define MM4(fm_, a_, b_) do {                                                     \
        MFMA(a_[fm_], b_[0], acc[fm_][0]);                                        \
        MFMA(a_[fm_], b_[1], acc[fm_][1]);                                        \
        MFMA(a_[fm_], b_[2], acc[fm_][2]);                                        \
        MFMA(a_[fm_], b_[3], acc[fm_][3]);                                        \
    } while (0)

#define STEP(u_, AR_, BR_, AM_, BM_) do {                                         \
        if ((u_) + 2 <= 31) STAGE((u_) + 2);                                      \
        const char* bp_ = lds + (((u_) & 3) * 32768);                             \
        RDA(AR_, bp_, 0); RDA(AR_, bp_, 1); RDA(AR_, bp_, 2);                     \
        MM4(0, AM_, BM_); MM4(1, AM_, BM_);                                       \
        RDA(AR_, bp_, 3); RDA(AR_, bp_, 4); RDA(AR_, bp_, 5);                     \
        MM4(2, AM_, BM_); MM4(3, AM_, BM_);                                       \
        RDA(AR_, bp_, 6); RDA(AR_, bp_, 7); RDB(BR_, bp_, 0);                     \
        MM4(4, AM_, BM_); MM4(5, AM_, BM_);                                       \
        RDB(BR_, bp_, 1); RDB(BR_, bp_, 2); RDB(BR_, bp_, 3);                     \
        MM4(6, AM_, BM_); MM4(7, AM_, BM_);                                       \
        if ((u_) <= 29) asm volatile("s_waitcnt vmcnt(4)" ::: "memory");          \
        else            asm volatile("s_waitcnt vmcnt(0)" ::: "memory");          \
        __builtin_amdgcn_s_barrier();                                             \
    } while (0)

    f32x4 acc[8][4] = {};
    s16x8 a0[8], b0[4], a1[8], b1[4];

    STAGE(0); STAGE(1); STAGE(2);
    asm volatile("s_waitcnt vmcnt(4)" ::: "memory");   // t0,t1 done; t2 in flight
    __builtin_amdgcn_s_barrier();
    {
        const char* bp_ = lds;
        RDA(a0, bp_, 0); RDA(a0, bp_, 1); RDA(a0, bp_, 2); RDA(a0, bp_, 3);
        RDA(a0, bp_, 4); RDA(a0, bp_, 5); RDA(a0, bp_, 6); RDA(a0, bp_, 7);
        RDB(b0, bp_, 0); RDB(b0, bp_, 1); RDB(b0, bp_, 2); RDB(b0, bp_, 3);
    }

    for (int tt = 0; tt < 15; ++tt) {
        STEP(2 * tt + 1, a1, b1, a0, b0);
        STEP(2 * tt + 2, a0, b0, a1, b1);
    }
    STEP(31, a1, b1, a0, b0);
    MM4(0, a1, b1); MM4(1, a1, b1); MM4(2, a1, b1); MM4(3, a1, b1);
    MM4(4, a1, b1); MM4(5, a1, b1); MM4(6, a1, b1); MM4(7, a1, b1);

#undef STAGE
#undef RDA
#undef RDB
#undef MM4
#undef STEP

    const float* bias = (nmat == 0) ? biasK : (nmat == 1) ? biasQ : biasV;
    u16* outKQ = (nmat == 0) ? Kb : Qb;
    const int colbase = ncol * 256 + wc * 64;
#pragma unroll
    for (int FM = 0; FM < 8; ++FM) {
#pragma unroll
        for (int fn = 0; fn < 4; ++fn) {
            const int col = colbase + fn * 16 + l15;
            const float bvv = bias[col];
            const int rbase = mt * 256 + wr * 128 + FM * 16 + (l16 << 2);
#pragma unroll
            for (int j = 0; j < 4; ++j) {
                const int row = rbase + j;
                const u16 hb = f2bf(acc[FM][fn][j] + bvv);
                if (nmat == 2) {
                    const int b = row >> 8, tt2 = row & 255;
                    Vt[(size_t)b * 262144 + (size_t)col * 256 + tt2] = hb;
                } else {
                    outKQ[(size_t)row * 1024 + col] = hb;
                }
            }
        }
    }
}

// ---------------- R1 reg-staged 128x128 mainloop (scores / pv) ----------------
__device__ inline void gemm_mainloop(const u16* __restrict__ Ap, const u16* __restrict__ Bp,
                                     int lda, int ldb, int kLen,
                                     u16* As, u16* Bs, f32x4 (&acc)[4][4]) {
    const int tid  = threadIdx.x;
    const int lane = tid & 63;
    const int wr   = (tid >> 7) & 1;
    const int wc   = (tid >> 6) & 1;
    const int sr   = tid >> 3;
    const int sc   = (tid & 7) << 3;

    for (int k0 = 0; k0 < kLen; k0 += 64) {
#pragma unroll
        for (int it = 0; it < 4; ++it) {
            int r = it * 32 + sr;
            *reinterpret_cast<s16x8*>(&As[r * 64 + sc]) =
                *reinterpret_cast<const s16x8*>(&Ap[(size_t)r * lda + k0 + sc]);
            *reinterpret_cast<s16x8*>(&Bs[r * 64 + sc]) =
                *reinterpret_cast<const s16x8*>(&Bp[(size_t)r * ldb + k0 + sc]);
        }
        __syncthreads();
#pragma unroll
        for (int kk = 0; kk < 64; kk += 32) {
            const int kcol = kk + (lane >> 4) * 8;
            s16x8 a[4], bfr[4];
#pragma unroll
            for (int m = 0; m < 4; ++m)
                a[m] = *reinterpret_cast<const s16x8*>(&As[(wr * 64 + m * 16 + (lane & 15)) * 64 + kcol]);
#pragma unroll
            for (int n = 0; n < 4; ++n)
                bfr[n] = *reinterpret_cast<const s16x8*>(&Bs[(wc * 64 + n * 16 + (lane & 15)) * 64 + kcol]);
#pragma unroll
            for (int m = 0; m < 4; ++m)
#pragma unroll
                for (int n = 0; n < 4; ++n)
                    acc[m][n] = __builtin_amdgcn_mfma_f32_16x16x32_bf16(a[m], bfr[n], acc[m][n], 0, 0, 0);
        }
        __syncthreads();
    }
}

// ---------------- scores: S = tril(Q K^T * 1/32) per batch ----------------
__global__ __launch_bounds__(256) void scores_gemm(const u16* __restrict__ Qb,
                                                   const u16* __restrict__ Kb,
                                                   float* __restrict__ S) {
    __shared__ u16 As[128 * 64];
    __shared__ u16 Bs[128 * 64];
    const int bid = blockIdx.x;
    const int b   = bid / 3;
    const int rem = bid % 3;
    const int ti  = (rem == 0) ? 0 : 1;
    const int si  = (rem == 2) ? 1 : 0;
    const u16* Ap = Qb + ((size_t)b * 256 + (size_t)ti * 128) * 1024;
    const u16* Bp = Kb + ((size_t)b * 256 + (size_t)si * 128) * 1024;

    f32x4 acc[4][4] = {};
    gemm_mainloop(Ap, Bp, 1024, 1024, 1024, As, Bs, acc);

    const int tid  = threadIdx.x;
    const int lane = tid & 63;
    const int wr   = (tid >> 7) & 1;
    const int wc   = (tid >> 6) & 1;
    const int r0 = (lane >> 4) << 2;
    const int c0 = lane & 15;
    const float scale = 0.03125f;
#pragma unroll
    for (int m = 0; m < 4; ++m) {
#pragma unroll
        for (int n = 0; n < 4; ++n) {
            const int s = si * 128 + wc * 64 + n * 16 + c0;
#pragma unroll
            for (int j = 0; j < 4; ++j) {
                const int t = ti * 128 + wr * 64 + m * 16 + r0 + j;
                float v = acc[m][n][j] * scale;
                if (s > t) v = -__builtin_inff();
                S[(size_t)b * 65536 + (size_t)t * 256 + s] = v;
            }
        }
    }
}

// ---------------- row softmax -> P (bf16), zeros above diagonal ----------------
__global__ __launch_bounds__(256) void softmax_p(const float* __restrict__ S, u16* __restrict__ P) {
    const int row  = blockIdx.x * 4 + (threadIdx.x >> 6);
    const int lane = threadIdx.x & 63;
    const int b = row >> 8, t = row & 255;
    const float* Sp = S + (size_t)b * 65536 + (size_t)t * 256;
    const int s0 = lane * 4;
    float4 v = reinterpret_cast<const float4*>(Sp)[lane];
    const float NEG = -__builtin_inff();
    float x0 = (s0 + 0 <= t) ? v.x : NEG;
    float x1 = (s0 + 1 <= t) ? v.y : NEG;
    float x2 = (s0 + 2 <= t) ? v.z : NEG;
    float x3 = (s0 + 3 <= t) ? v.w : NEG;
    float mx = fmaxf(fmaxf(x0, x1), fmaxf(x2, x3));
#pragma unroll
    for (int off = 1; off < 64; off <<= 1) mx = fmaxf(mx, __shfl_xor(mx, off, 64));
    float e0 = (s0 + 0 <= t) ? __expf(x0 - mx) : 0.f;
    float e1 = (s0 + 1 <= t) ? __expf(x1 - mx) : 0.f;
    float e2 = (s0 + 2 <= t) ? __expf(x2 - mx) : 0.f;
    float e3 = (s0 + 3 <= t) ? __expf(x3 - mx) : 0.f;
    float sum = e0 + e1 + e2 + e3;
#pragma unroll
    for (int off = 1; off < 64; off <<= 1) sum += __shfl_xor(sum, off, 64);
    const float inv = 1.0f / sum;
    ushort4 o = make_ushort4(f2bf(e0 * inv), f2bf(e1 * inv), f2bf(e2 * inv), f2bf(e3 * inv));
    reinterpret_cast<ushort4*>(P + (size_t)row * 256)[lane] = o;
}

// ---------------- PV: out = P @ V  (Vt is [b][d][t] so NT) ----------------
__global__ __launch_bounds__(256) void pv_gemm(const u16* __restrict__ P, const u16* __restrict__ Vt,
                                               float* __restrict__ O) {
    __shared__ u16 As[128 * 64];
    __shared__ u16 Bs[128 * 64];
    const int bid = blockIdx.x;
    const int b   = bid >> 4;
    const int r   = bid & 15;
    const int mt  = r >> 3;
    const int ntl = r & 7;
    const u16* Ap = P + (size_t)b * 65536 + (size_t)mt * 128 * 256;
    const u16* Bp = Vt + (size_t)b * 262144 + (size_t)ntl * 128 * 256;
    const int kmax = (mt + 1) * 128;

    f32x4 acc[4][4] = {};
    gemm_mainloop(Ap, Bp, 256, 256, kmax, As, Bs, acc);

    const int tid  = threadIdx.x;
    const int lane = tid & 63;
    const int wr   = (tid >> 7) & 1;
    const int wc   = (tid >> 6) & 1;
    const int r0 = (lane >> 4) << 2;
    const int c0 = lane & 15;
#pragma unroll
    for (int m = 0; m < 4; ++m) {
#pragma unroll
        for (int n = 0; n < 4; ++n) {
            const int d = ntl * 128 + wc * 64 + n * 16 + c0;
#pragma unroll
            for (int j = 0; j < 4; ++j) {
                const int t = mt * 128 + wr * 64 + m * 16 + r0 + j;
                O[((size_t)b * 256 + t) * 1024 + d] = acc[m][n][j];
            }
        }
    }
}

// ---------------- launcher ----------------
extern "C" void kernel_launch(void* const* d_in, const int* in_sizes, int n_in,
                              void* d_out, int out_size, void* d_ws, size_t ws_size,
                              hipStream_t stream) {
    (void)in_sizes; (void)n_in; (void)out_size; (void)ws_size;
    const float* x  = (const float*)d_in[0];
    const float* Wk = (const float*)d_in[1];
    const float* bk = (const float*)d_in[2];
    const float* Wq = (const float*)d_in[3];
    const float* bq = (const float*)d_in[4];
    const float* Wv = (const float*)d_in[5];
    const float* bv = (const float*)d_in[6];
    float* out = (float*)d_out;
    char* ws = (char*)d_ws;

    // ws layout (bytes):
    //   [0,            67108864)  xb  bf16 x [32768][1024]  (dead after qkv)
    //   [67108864,     73400320)  Wb  bf16 Wk|Wq|Wv
    //   [73400320,    140509184)  Kb ; [140509184, 207618048) Qb
    //   [207618048,   274726912)  Vt  bf16 values^T [128][1024][256]
    //   overlay after qkv: S f32 [128][256][256] at 0 ; P bf16 at 33554432
    u16*   xb = (u16*)(ws + 0);
    u16*   Wb = (u16*)(ws + 67108864);
    u16*   Kb = (u16*)(ws + 73400320);
    u16*   Qb = (u16*)(ws + 140509184);
    u16*   Vt = (u16*)(ws + 207618048);
    float* S  = (float*)(ws + 0);
    u16*   P  = (u16*)(ws + 33554432);

    cvt_f32_bf16<<<2048, 256, 0, stream>>>(x, xb, 33554432 / 4);
    cvt_w3<<<1536, 256, 0, stream>>>(Wk, Wq, Wv, Wb);
    qkv256<<<1536, 512, 131072, stream>>>(xb, Wb, bk, bq, bv, Kb, Qb, Vt);
    scores_gemm<<<384, 256, 0, stream>>>(Qb, Kb, S);
    softmax_p<<<8192, 256, 0, stream>>>(S, P);
    pv_gemm<<<2048, 256, 0, stream>>>(P, Vt, out);
}

// Round 17
// 393.535 us; speedup vs baseline: 1.0261x; 1.0106x over previous
//
#include <hip/hip_runtime.h>
#include <hip/hip_bf16.h>

// Problem: B=128, T=256, D=1024.  TOK = B*T = 32768.
// keys = x@Wk.T+bk ; queries = x@Wq.T+bq ; values = x@Wv.T+bv
// S = tril(Q K^T / 32) ; P = softmax(S) ; out = P V   (fp32 out)
//
// CONFIG: converged 397.7us pipeline + ONE change: pad-72 LDS stride in the
// reg-staged scores/pv mainloop (kills the 16-way stride-128B read conflict;
// legal because reg-staged).  qkv256/converts/softmax byte-identical.

typedef __attribute__((ext_vector_type(4))) float f32x4;
typedef __attribute__((ext_vector_type(8))) short s16x8;
typedef unsigned short u16;

__device__ inline u16 f2bf(float f) {
    union { __hip_bfloat16 h; u16 u; } c;
    c.h = __float2bfloat16(f);
    return c.u;
}

// async global->LDS DMA, 16B/lane, dest = wave-uniform base + lane*16
__device__ __forceinline__ void stage16(const void* g, void* l) {
    __builtin_amdgcn_global_load_lds((const __attribute__((address_space(1))) void*)g,
                                     (__attribute__((address_space(3))) void*)l, 16, 0, 0);
}

#define MFMA(a_, b_, c_) (c_) = __builtin_amdgcn_mfma_f32_16x16x32_bf16((a_), (b_), (c_), 0, 0, 0)

// ---------------- fp32 -> bf16 convert (x) ----------------
__global__ __launch_bounds__(256) void cvt_f32_bf16(const float* __restrict__ in,
                                                    u16* __restrict__ out, int n4) {
    int stride = gridDim.x * blockDim.x;
    for (int i = blockIdx.x * blockDim.x + threadIdx.x; i < n4; i += stride) {
        float4 v = reinterpret_cast<const float4*>(in)[i];
        ushort4 o = make_ushort4(f2bf(v.x), f2bf(v.y), f2bf(v.z), f2bf(v.w));
        reinterpret_cast<ushort4*>(out)[i] = o;
    }
}

// ---------------- fp32 -> bf16 convert, 3 weights in one launch ----------------
__global__ __launch_bounds__(256) void cvt_w3(const float* __restrict__ Wk,
                                              const float* __restrict__ Wq,
                                              const float* __restrict__ Wv,
                                              u16* __restrict__ Wb) {
    const int wsel = blockIdx.x / 512;          // 0:K 1:Q 2:V
    const int blk  = blockIdx.x % 512;
    const float* src = (wsel == 0) ? Wk : (wsel == 1) ? Wq : Wv;
    u16* dst = Wb + (size_t)wsel * 1048576;
    const int i = blk * 256 + threadIdx.x;
    {
        float4 v = reinterpret_cast<const float4*>(src)[i];
        ushort4 o = make_ushort4(f2bf(v.x), f2bf(v.y), f2bf(v.z), f2bf(v.w));
        reinterpret_cast<ushort4*>(dst)[i] = o;
        float4 v2 = reinterpret_cast<const float4*>(src)[i + 131072];
        ushort4 o2 = make_ushort4(f2bf(v2.x), f2bf(v2.y), f2bf(v2.z), f2bf(v2.w));
        reinterpret_cast<ushort4*>(dst)[i + 131072] = o2;
    }
}

// ======== R7 qkv256 VERBATIM (best measured: ~300us, 687 TF) ========
__global__ __launch_bounds__(512, 2) void qkv256(const u16* __restrict__ X, const u16* __restrict__ W3,
                                                 const float* __restrict__ biasK,
                                                 const float* __restrict__ biasQ,
                                                 const float* __restrict__ biasV,
                                                 u16* __restrict__ Kb, u16* __restrict__ Qb,
                                                 u16* __restrict__ Vt) {
    extern __shared__ char lds[];  // 131072 B = 4 bufs * 32768

    const int bid = blockIdx.x;
    const int swz = (bid & 7) * 192 + (bid >> 3);  // 1536 % 8 == 0: bijective XCD swizzle
    const int mt = swz / 12, nt2 = swz % 12;
    const int nmat = nt2 >> 2, ncol = nt2 & 3;
    const u16* Asrc = X + (size_t)mt * 256 * 1024;
    const u16* Bsrc = W3 + (size_t)nmat * 1048576 + (size_t)ncol * 256 * 1024;

    const int tid  = threadIdx.x;
    const int lane = tid & 63, w = tid >> 6;
    const int wr = w >> 2, wc = w & 3;
    const int l15 = lane & 15, l16 = lane >> 4;

    const int lds_ro = l15 * 64 + ((l16 ^ ((l15 >> 1) & 3)) << 4);
    const int aoff = wr * 128 * 64 + lds_ro;
    const int boff = 16384 + wc * 64 * 64 + lds_ro;

    const int isB = w >> 2;
    const u16* dsrc = isB ? Bsrc : Asrc;
    const int drow  = (w & 3) * 64 + (lane >> 2);
    const int dslot = ((lane & 3) ^ ((lane >> 3) & 3)) * 8;
    const u16* dptr0 = dsrc + (size_t)drow * 1024 + dslot;
    const int dlds = isB * 16384 + (w & 3) * 4096;

#define STAGE(u_) do {                                                            \
        char* bb_ = lds + (((u_) & 3) * 32768) + dlds;                            \
        const u16* gp_ = dptr0 + (size_t)(u_) * 32;                               \
        stage16(gp_,             bb_);                                            \
        stage16(gp_ + 16 * 1024, bb_ + 1024);                                     \
        stage16(gp_ + 32 * 1024, bb_ + 2048);                                     \
        stage16(gp_ + 48 * 1024, bb_ + 3072);                                     \
    } while (0)

#define RDA(d_, bp_, fm_) d_[fm_] = *(const s16x8*)((bp_) + aoff + (fm_) * 1024)
#define RDB(d_, bp_, fn_) d_[fn_] = *(const s16x8*)((bp_) + boff + (fn_) * 1024)

#define MM4(fm_, a_, b_) do {                                                     \
        MFMA(a_[fm_], b_[0], acc[fm_][0]);                                        \
        MFMA(a_[fm_], b_[1], acc[fm_][1]);                                        \
        MFMA(a_[fm_], b_[2], acc[fm_][2]);                                        \
        MFMA(a_[fm_], b_[3], acc[fm_][3]);                                        \
    } while (0)

#define STEP(u_, AR_, BR_, AM_, BM_) do {                                         \
        if ((u_) + 2 <= 31) STAGE((u_) + 2);                                      \
        const char* bp_ = lds + (((u_) & 3) * 32768);                             \
        RDA(AR_, bp_, 0); RDA(AR_, bp_, 1); RDA(AR_, bp_, 2);                     \
        MM4(0, AM_, BM_); MM4(1, AM_, BM_);                                       \
        RDA(AR_, bp_, 3); RDA(AR_, bp_, 4); RDA(AR_, bp_, 5);                     \
        MM4(2, AM_, BM_); MM4(3, AM_, BM_);                                       \
        RDA(AR_, bp_, 6); RDA(AR_, bp_, 7); RDB(BR_, bp_, 0);                     \
        MM4(4, AM_, BM_); MM4(5, AM_, BM_);                                       \
        RDB(BR_, bp_, 1); RDB(BR_, bp_, 2); RDB(BR_, bp_, 3);                     \
        MM4(6, AM_, BM_); MM4(7, AM_, BM_);                                       \
        if ((u_) <= 29) asm volatile("s_waitcnt vmcnt(4)" ::: "memory");          \
        else            asm volatile("s_waitcnt vmcnt(0)" ::: "memory");          \
        __builtin_amdgcn_s_barrier();                                             \
    } while (0)

    f32x4 acc[8][4] = {};
    s16x8 a0[8], b0[4], a1[8], b1[4];

    STAGE(0); STAGE(1); STAGE(2);
    asm volatile("s_waitcnt vmcnt(4)" ::: "memory");   // t0,t1 done; t2 in flight
    __builtin_amdgcn_s_barrier();
    {
        const char* bp_ = lds;
        RDA(a0, bp_, 0); RDA(a0, bp_, 1); RDA(a0, bp_, 2); RDA(a0, bp_, 3);
        RDA(a0, bp_, 4); RDA(a0, bp_, 5); RDA(a0, bp_, 6); RDA(a0, bp_, 7);
        RDB(b0, bp_, 0); RDB(b0, bp_, 1); RDB(b0, bp_, 2); RDB(b0, bp_, 3);
    }

    for (int tt = 0; tt < 15; ++tt) {
        STEP(2 * tt + 1, a1, b1, a0, b0);
        STEP(2 * tt + 2, a0, b0, a1, b1);
    }
    STEP(31, a1, b1, a0, b0);
    MM4(0, a1, b1); MM4(1, a1, b1); MM4(2, a1, b1); MM4(3, a1, b1);
    MM4(4, a1, b1); MM4(5, a1, b1); MM4(6, a1, b1); MM4(7, a1, b1);

#undef STAGE
#undef RDA
#undef RDB
#undef MM4
#undef STEP

    const float* bias = (nmat == 0) ? biasK : (nmat == 1) ? biasQ : biasV;
    u16* outKQ = (nmat == 0) ? Kb : Qb;
    const int colbase = ncol * 256 + wc * 64;
#pragma unroll
    for (int FM = 0; FM < 8; ++FM) {
#pragma unroll
        for (int fn = 0; fn < 4; ++fn) {
            const int col = colbase + fn * 16 + l15;
            const float bvv = bias[col];
            const int rbase = mt * 256 + wr * 128 + FM * 16 + (l16 << 2);
#pragma unroll
            for (int j = 0; j < 4; ++j) {
                const int row = rbase + j;
                const u16 hb = f2bf(acc[FM][fn][j] + bvv);
                if (nmat == 2) {
                    const int b = row >> 8, tt2 = row & 255;
                    Vt[(size_t)b * 262144 + (size_t)col * 256 + tt2] = hb;
                } else {
                    outKQ[(size_t)row * 1024 + col] = hb;
                }
            }
        }
    }
}

// ---------------- reg-staged 128x128 mainloop (scores / pv), pad-72 ----------------
// LDS stride 72 elems (144B): lanes' stride-1-row reads now walk banks instead
// of hitting one bank 16-way.  Reg-staged ds_write, so padding is legal.
__device__ inline void gemm_mainloop(const u16* __restrict__ Ap, const u16* __restrict__ Bp,
                                     int lda, int ldb, int kLen,
                                     u16* As, u16* Bs, f32x4 (&acc)[4][4]) {
    const int tid  = threadIdx.x;
    const int lane = tid & 63;
    const int wr   = (tid >> 7) & 1;
    const int wc   = (tid >> 6) & 1;
    const int sr   = tid >> 3;
    const int sc   = (tid & 7) << 3;

    for (int k0 = 0; k0 < kLen; k0 += 64) {
#pragma unroll
        for (int it = 0; it < 4; ++it) {
            int r = it * 32 + sr;
            *reinterpret_cast<s16x8*>(&As[r * 72 + sc]) =
                *reinterpret_cast<const s16x8*>(&Ap[(size_t)r * lda + k0 + sc]);
            *reinterpret_cast<s16x8*>(&Bs[r * 72 + sc]) =
                *reinterpret_cast<const s16x8*>(&Bp[(size_t)r * ldb + k0 + sc]);
        }
        __syncthreads();
#pragma unroll
        for (int kk = 0; kk < 64; kk += 32) {
            const int kcol = kk + (lane >> 4) * 8;
            s16x8 a[4], bfr[4];
#pragma unroll
            for (int m = 0; m < 4; ++m)
                a[m] = *reinterpret_cast<const s16x8*>(&As[(wr * 64 + m * 16 + (lane & 15)) * 72 + kcol]);
#pragma unroll
            for (int n = 0; n < 4; ++n)
                bfr[n] = *reinterpret_cast<const s16x8*>(&Bs[(wc * 64 + n * 16 + (lane & 15)) * 72 + kcol]);
#pragma unroll
            for (int m = 0; m < 4; ++m)
#pragma unroll
                for (int n = 0; n < 4; ++n)
                    acc[m][n] = __builtin_amdgcn_mfma_f32_16x16x32_bf16(a[m], bfr[n], acc[m][n], 0, 0, 0);
        }
        __syncthreads();
    }
}

// ---------------- scores: S = tril(Q K^T * 1/32) per batch ----------------
__global__ __launch_bounds__(256) void scores_gemm(const u16* __restrict__ Qb,
                                                   const u16* __restrict__ Kb,
                                                   float* __restrict__ S) {
    __shared__ u16 As[128 * 72];
    __shared__ u16 Bs[128 * 72];
    const int bid = blockIdx.x;
    const int b   = bid / 3;
    const int rem = bid % 3;
    const int ti  = (rem == 0) ? 0 : 1;
    const int si  = (rem == 2) ? 1 : 0;
    const u16* Ap = Qb + ((size_t)b * 256 + (size_t)ti * 128) * 1024;
    const u16* Bp = Kb + ((size_t)b * 256 + (size_t)si * 128) * 1024;

    f32x4 acc[4][4] = {};
    gemm_mainloop(Ap, Bp, 1024, 1024, 1024, As, Bs, acc);

    const int tid  = threadIdx.x;
    const int lane = tid & 63;
    const int wr   = (tid >> 7) & 1;
    const int wc   = (tid >> 6) & 1;
    const int r0 = (lane >> 4) << 2;
    const int c0 = lane & 15;
    const float scale = 0.03125f;
#pragma unroll
    for (int m = 0; m < 4; ++m) {
#pragma unroll
        for (int n = 0; n < 4; ++n) {
            const int s = si * 128 + wc * 64 + n * 16 + c0;
#pragma unroll
            for (int j = 0; j < 4; ++j) {
                const int t = ti * 128 + wr * 64 + m * 16 + r0 + j;
                float v = acc[m][n][j] * scale;
                if (s > t) v = -__builtin_inff();
                S[(size_t)b * 65536 + (size_t)t * 256 + s] = v;
            }
        }
    }
}

// ---------------- row softmax -> P (bf16), zeros above diagonal ----------------
__global__ __launch_bounds__(256) void softmax_p(const float* __restrict__ S, u16* __restrict__ P) {
    const int row  = blockIdx.x * 4 + (threadIdx.x >> 6);
    const int lane = threadIdx.x & 63;
    const int b = row >> 8, t = row & 255;
    const float* Sp = S + (size_t)b * 65536 + (size_t)t * 256;
    const int s0 = lane * 4;
    float4 v = reinterpret_cast<const float4*>(Sp)[lane];
    const float NEG = -__builtin_inff();
    float x0 = (s0 + 0 <= t) ? v.x : NEG;
    float x1 = (s0 + 1 <= t) ? v.y : NEG;
    float x2 = (s0 + 2 <= t) ? v.z : NEG;
    float x3 = (s0 + 3 <= t) ? v.w : NEG;
    float mx = fmaxf(fmaxf(x0, x1), fmaxf(x2, x3));
#pragma unroll
    for (int off = 1; off < 64; off <<= 1) mx = fmaxf(mx, __shfl_xor(mx, off, 64));
    float e0 = (s0 + 0 <= t) ? __expf(x0 - mx) : 0.f;
    float e1 = (s0 + 1 <= t) ? __expf(x1 - mx) : 0.f;
    float e2 = (s0 + 2 <= t) ? __expf(x2 - mx) : 0.f;
    float e3 = (s0 + 3 <= t) ? __expf(x3 - mx) : 0.f;
    float sum = e0 + e1 + e2 + e3;
#pragma unroll
    for (int off = 1; off < 64; off <<= 1) sum += __shfl_xor(sum, off, 64);
    const float inv = 1.0f / sum;
    ushort4 o = make_ushort4(f2bf(e0 * inv), f2bf(e1 * inv), f2bf(e2 * inv), f2bf(e3 * inv));
    reinterpret_cast<ushort4*>(P + (size_t)row * 256)[lane] = o;
}

// ---------------- PV: out = P @ V  (Vt is [b][d][t] so NT) ----------------
__global__ __launch_bounds__(256) void pv_gemm(const u16* __restrict__ P, const u16* __restrict__ Vt,
                                               float* __restrict__ O) {
    __shared__ u16 As[128 * 72];
    __shared__ u16 Bs[128 * 72];
    const int bid = blockIdx.x;
    const int b   = bid >> 4;
    const int r   = bid & 15;
    const int mt  = r >> 3;
    const int ntl = r & 7;
    const u16* Ap = P + (size_t)b * 65536 + (size_t)mt * 128 * 256;
    const u16* Bp = Vt + (size_t)b * 262144 + (size_t)ntl * 128 * 256;
    const int kmax = (mt + 1) * 128;

    f32x4 acc[4][4] = {};
    gemm_mainloop(Ap, Bp, 256, 256, kmax, As, Bs, acc);

    const int tid  = threadIdx.x;
    const int lane = tid & 63;
    const int wr   = (tid >> 7) & 1;
    const int wc   = (tid >> 6) & 1;
    const int r0 = (lane >> 4) << 2;
    const int c0 = lane & 15;
#pragma unroll
    for (int m = 0; m < 4; ++m) {
#pragma unroll
        for (int n = 0; n < 4; ++n) {
            const int d = ntl * 128 + wc * 64 + n * 16 + c0;
#pragma unroll
            for (int j = 0; j < 4; ++j) {
                const int t = mt * 128 + wr * 64 + m * 16 + r0 + j;
                O[((size_t)b * 256 + t) * 1024 + d] = acc[m][n][j];
            }
        }
    }
}

// ---------------- launcher ----------------
extern "C" void kernel_launch(void* const* d_in, const int* in_sizes, int n_in,
                              void* d_out, int out_size, void* d_ws, size_t ws_size,
                              hipStream_t stream) {
    (void)in_sizes; (void)n_in; (void)out_size; (void)ws_size;
    const float* x  = (const float*)d_in[0];
    const float* Wk = (const float*)d_in[1];
    const float* bk = (const float*)d_in[2];
    const float* Wq = (const float*)d_in[3];
    const float* bq = (const float*)d_in[4];
    const float* Wv = (const float*)d_in[5];
    const float* bv = (const float*)d_in[6];
    float* out = (float*)d_out;
    char* ws = (char*)d_ws;

    // ws layout (bytes):
    //   [0,            67108864)  xb  bf16 x [32768][1024]  (dead after qkv)
    //   [67108864,     73400320)  Wb  bf16 Wk|Wq|Wv
    //   [73400320,    140509184)  Kb ; [140509184, 207618048) Qb
    //   [207618048,   274726912)  Vt  bf16 values^T [128][1024][256]
    //   overlay after qkv: S f32 [128][256][256] at 0 ; P bf16 at 33554432
    u16*   xb = (u16*)(ws + 0);
    u16*   Wb = (u16*)(ws + 67108864);
    u16*   Kb = (u16*)(ws + 73400320);
    u16*   Qb = (u16*)(ws + 140509184);
    u16*   Vt = (u16*)(ws + 207618048);
    float* S  = (float*)(ws + 0);
    u16*   P  = (u16*)(ws + 33554432);

    cvt_f32_bf16<<<2048, 256, 0, stream>>>(x, xb, 33554432 / 4);
    cvt_w3<<<1536, 256, 0, stream>>>(Wk, Wq, Wv, Wb);
    qkv256<<<1536, 512, 131072, stream>>>(xb, Wb, bk, bq, bv, Kb, Qb, Vt);
    scores_gemm<<<384, 256, 0, stream>>>(Qb, Kb, S);
    softmax_p<<<8192, 256, 0, stream>>>(S, P);
    pv_gemm<<<2048, 256, 0, stream>>>(P, Vt, out);
}